// Round 14
// baseline (227.405 us; speedup 1.0000x reference)
//
#include <hip/hip_runtime.h>

#define TD 256  // feature dim

typedef __attribute__((ext_vector_type(8))) short short8;
typedef __attribute__((ext_vector_type(8))) unsigned short ushort8;
typedef __attribute__((ext_vector_type(4))) float f32x4;

__device__ inline unsigned short f2bf(float f) {
  unsigned u = __float_as_uint(f);
  u = u + 0x7fffu + ((u >> 16) & 1u);  // round-to-nearest-even
  return (unsigned short)(u >> 16);
}
__device__ inline float bf2f(unsigned short h) {
  return __uint_as_float(((unsigned)h) << 16);
}

// ===========================================================================
// Prologue mega-kernel: hist | x->bf16 | Wq,Wk row-major bf16 | W0,W1,Wv^T bf16
// ===========================================================================
__global__ __launch_bounds__(256) void prologue_kernel(
    const int* __restrict__ ei, int E1, const int* __restrict__ ei2, int E2,
    int* __restrict__ deg1, int* __restrict__ deg2,
    const float* __restrict__ x, unsigned short* __restrict__ xb, long total8,
    const float* __restrict__ Wq, const float* __restrict__ Wk,
    unsigned short* __restrict__ wqb, unsigned short* __restrict__ wkb,
    const float* __restrict__ W0, const float* __restrict__ W1,
    const float* __restrict__ Wv, unsigned short* __restrict__ wt,
    int nbH, int nbX) {
  int b = blockIdx.x;
  if (b < nbH) {
    int stride = nbH * 256;
    int Emax = max(E1, E2);
    for (int i = b * 256 + threadIdx.x; i < Emax; i += stride) {
      if (i < E1) atomicAdd(&deg1[ei[E1 + i]], 1);
      if (i < E2) atomicAdd(&deg2[ei2[E2 + i]], 1);
    }
  } else if (b < nbH + nbX) {
    long t = (long)(b - nbH) * 256 + threadIdx.x;
    if (t >= total8) return;
    const float4 f0 = *reinterpret_cast<const float4*>(x + t * 8);
    const float4 f1 = *reinterpret_cast<const float4*>(x + t * 8 + 4);
    ushort8 o;
    o[0] = f2bf(f0.x); o[1] = f2bf(f0.y); o[2] = f2bf(f0.z); o[3] = f2bf(f0.w);
    o[4] = f2bf(f1.x); o[5] = f2bf(f1.y); o[6] = f2bf(f1.z); o[7] = f2bf(f1.w);
    *reinterpret_cast<ushort8*>(xb + t * 8) = o;
  } else if (b < nbH + nbX + 64) {
    int t = (b - nbH - nbX) * 256 + threadIdx.x;  // 0..16383
    const float* src = (t < 8192) ? Wq : Wk;
    unsigned short* dst = (t < 8192) ? wqb : wkb;
    int o = (t & 8191) * 8;
    ushort8 r;
#pragma unroll
    for (int j = 0; j < 8; j++) r[j] = f2bf(src[o + j]);
    *reinterpret_cast<ushort8*>(dst + o) = r;
  } else {
    int b2 = b - nbH - nbX - 64;  // 0..767
    int m = b2 >> 8;
    int n = b2 & 255;
    int k = threadIdx.x;
    const float* W = m == 0 ? W0 : m == 1 ? W1 : Wv;
    wt[m * 65536 + n * 256 + k] = f2bf(W[k * 256 + n]);
  }
}

// ===========================================================================
// scan phase A (blocks 0..511) + gemmG (blocks 512..515)
// ===========================================================================
__global__ __launch_bounds__(256) void scanA_gemmG_kernel(
    const int* __restrict__ deg1, const int* __restrict__ deg2, int N,
    int* __restrict__ bsum,
    const unsigned short* __restrict__ wqb, const unsigned short* __restrict__ wkb,
    unsigned short* __restrict__ gt) {
  if (blockIdx.x < 512) {
    int arr = blockIdx.x >> 8;
    int b = blockIdx.x & 255;
    const int* deg = arr ? deg2 : deg1;
    int i = b * 256 + threadIdx.x;
    int v = (i < N) ? deg[i] : 0;
#pragma unroll
    for (int m = 1; m < 64; m <<= 1) v += __shfl_xor(v, m, 64);
    __shared__ int wsum[4];
    if ((threadIdx.x & 63) == 0) wsum[threadIdx.x >> 6] = v;
    __syncthreads();
    if (threadIdx.x == 0)
      bsum[blockIdx.x] = wsum[0] + wsum[1] + wsum[2] + wsum[3];
    return;
  }
  const int t = (blockIdx.x - 512) * 4 + (threadIdx.x >> 6);
  const int l = threadIdx.x & 63;
  const int a0 = (t >> 2) * 64;
  const int b0 = (t & 3) * 64;
  const int lc = l & 15;
  const int lk = l >> 4;
  f32x4 acc[4][4] = {};
#pragma unroll
  for (int ks = 0; ks < 256; ks += 32) {
    const int ko = ks + lk * 8;
    short8 a[4], b[4];
#pragma unroll
    for (int m = 0; m < 4; m++)
      a[m] = *reinterpret_cast<const short8*>(wqb + (a0 + m * 16 + lc) * 256 + ko);
#pragma unroll
    for (int n = 0; n < 4; n++)
      b[n] = *reinterpret_cast<const short8*>(wkb + (b0 + n * 16 + lc) * 256 + ko);
#pragma unroll
    for (int m = 0; m < 4; m++)
#pragma unroll
      for (int n = 0; n < 4; n++)
        acc[m][n] =
            __builtin_amdgcn_mfma_f32_16x16x32_bf16(a[m], b[n], acc[m][n], 0, 0, 0);
  }
#pragma unroll
  for (int m = 0; m < 4; m++)
#pragma unroll
    for (int n = 0; n < 4; n++)
#pragma unroll
      for (int j = 0; j < 4; j++) {
        int a = a0 + m * 16 + lk * 4 + j;
        int b = b0 + n * 16 + lc;
        gt[b * 256 + a] = f2bf(acc[m][n][j]);
      }
}

// ===========================================================================
// scan_fill with in-block bsum prefix.  grid = 512.  bsum = RAW block sums.
// ===========================================================================
__global__ __launch_bounds__(256) void scan_fill_kernel(
    const int* __restrict__ deg1, const int* __restrict__ deg2,
    const int* __restrict__ bsum, int N,
    int* __restrict__ off1, int* __restrict__ cur1,
    int* __restrict__ off2, int* __restrict__ cur2) {
  int arr = blockIdx.x >> 8;
  int b = blockIdx.x & 255;
  const int* deg = arr ? deg2 : deg1;
  int* off = arr ? off2 : off1;
  int* cur = arr ? cur2 : cur1;
  const int t = threadIdx.x;

  __shared__ int redp[4], redt[4];
  int sval = bsum[arr * 256 + t];
  int pv = (t < b) ? sval : 0;
  int tv = sval;
#pragma unroll
  for (int m = 1; m < 64; m <<= 1) {
    pv += __shfl_xor(pv, m, 64);
    tv += __shfl_xor(tv, m, 64);
  }
  if ((t & 63) == 0) { redp[t >> 6] = pv; redt[t >> 6] = tv; }
  __syncthreads();
  int prefix = redp[0] + redp[1] + redp[2] + redp[3];
  int total = redt[0] + redt[1] + redt[2] + redt[3];
  if (b == 255 && t == 0) off[N] = total;

  int i = b * 256 + t;
  __shared__ int sm[256];
  int v = (i < N) ? deg[i] : 0;
  sm[t] = v;
  __syncthreads();
  for (int d = 1; d < 256; d <<= 1) {
    int val = (t >= d) ? sm[t - d] : 0;
    __syncthreads();
    sm[t] += val;
    __syncthreads();
  }
  int e = sm[t] - v + prefix;
  if (i < N) {
    off[i] = e;
    cur[i] = e;
  }
}

// ===========================================================================
// Merged: blocks [0,FB) do CSR fill; blocks [FB, FB+gblk) do gemm0 (q'=x@Gt),
// round-5-proven KSTEP=64 / XOR-(row&7) GEMM body UNCHANGED.
// ===========================================================================
__global__ __launch_bounds__(512) void fill_gemm0_kernel(
    const int* __restrict__ ei, int E1, const int* __restrict__ ei2, int E2,
    int* __restrict__ cur1, int* __restrict__ cur2,
    int* __restrict__ csr1, int* __restrict__ csr2,
    const unsigned short* __restrict__ xb, const unsigned short* __restrict__ gt,
    unsigned short* __restrict__ qb, int M, int FB) {
  __shared__ __align__(16) unsigned short sA[128 * 64];
  __shared__ __align__(16) unsigned short sB[256 * 64];

  if (blockIdx.x < FB) {
    int stride = FB * 512;
    int Emax = max(E1, E2);
    for (int i = blockIdx.x * 512 + threadIdx.x; i < Emax; i += stride) {
      if (i < E1) {
        int d = ei[E1 + i];
        int p = atomicAdd(&cur1[d], 1);
        csr1[p] = ei[i];
      }
      if (i < E2) {
        int d = ei2[E2 + i];
        int p = atomicAdd(&cur2[d], 1);
        csr2[p] = ei2[i];
      }
    }
    return;
  }

  const int m0 = (blockIdx.x - FB) * 128;
  const int tid = threadIdx.x;
  const int w = tid >> 6, l = tid & 63;
  const int lrow = l >> 3, lslot = l & 7;
  const int wr = w >> 2, wc = w & 3;  // 2x4 wave grid, 64x64 each

  f32x4 acc[4][4] = {};

  for (int k0 = 0; k0 < 256; k0 += 64) {
    const unsigned short* Ap = xb;
    const unsigned short* Bp = gt;
    int ks = k0;

#pragma unroll
    for (int i = 0; i < 2; i++) {
      int row = w * 16 + i * 8 + lrow;
      int gr = m0 + row;
      if (gr >= M) gr = M - 1;
      int g = lslot ^ lrow;
      const unsigned short* src = Ap + (size_t)gr * TD + ks + g * 8;
      unsigned short* dst = sA + (w * 16 + i * 8) * 64;
      __builtin_amdgcn_global_load_lds(
          (const __attribute__((address_space(1))) void*)src,
          (__attribute__((address_space(3))) void*)dst, 16, 0, 0);
    }
#pragma unroll
    for (int i = 0; i < 4; i++) {
      int row = w * 32 + i * 8 + lrow;
      int g = lslot ^ lrow;
      const unsigned short* src = Bp + (size_t)row * TD + ks + g * 8;
      unsigned short* dst = sB + (w * 32 + i * 8) * 64;
      __builtin_amdgcn_global_load_lds(
          (const __attribute__((address_space(1))) void*)src,
          (__attribute__((address_space(3))) void*)dst, 16, 0, 0);
    }
    __syncthreads();

#pragma unroll
    for (int kk = 0; kk < 2; kk++) {
      short8 a[4], b[4];
#pragma unroll
      for (int m = 0; m < 4; m++) {
        int row = wr * 64 + m * 16 + (l & 15);
        int slot = (kk * 4 + (l >> 4)) ^ (row & 7);
        a[m] = *reinterpret_cast<const short8*>(&sA[row * 64 + slot * 8]);
      }
#pragma unroll
      for (int n = 0; n < 4; n++) {
        int row = wc * 64 + n * 16 + (l & 15);
        int slot = (kk * 4 + (l >> 4)) ^ (row & 7);
        b[n] = *reinterpret_cast<const short8*>(&sB[row * 64 + slot * 8]);
      }
#pragma unroll
      for (int m = 0; m < 4; m++)
#pragma unroll
        for (int n = 0; n < 4; n++)
          acc[m][n] =
              __builtin_amdgcn_mfma_f32_16x16x32_bf16(a[m], b[n], acc[m][n], 0, 0, 0);
    }
    __syncthreads();
  }

#pragma unroll
  for (int m = 0; m < 4; m++)
#pragma unroll
    for (int n = 0; n < 4; n++)
#pragma unroll
      for (int j = 0; j < 4; j++) {
        int r = m0 + wr * 64 + m * 16 + (l >> 4) * 4 + j;
        if (r < M)
          qb[(size_t)r * TD + wc * 64 + n * 16 + (l & 15)] = f2bf(acc[m][n][j]);
      }
}

// ===========================================================================
// Merged: blocks [0,gblk) compute out = x@W0 (MFMA, independent of gather);
// blocks [gblk, gblk+GB) do the fused gather (8 nodes/block, 8 waves of 64).
// gather leaves the MFMA pipe idle -> the GEMM rides along nearly free (m114).
// ===========================================================================
__global__ __launch_bounds__(512) void gather_xw0_kernel(
    const unsigned short* __restrict__ xb, const unsigned short* __restrict__ qb,
    const int* __restrict__ off1, const int* __restrict__ csr1,
    const int* __restrict__ off2, const int* __restrict__ csr2,
    int N, unsigned short* __restrict__ aggb, unsigned short* __restrict__ tb,
    const unsigned short* __restrict__ wt, float* __restrict__ out, int gblk) {
  __shared__ __align__(16) unsigned short sA[128 * 64];
  __shared__ __align__(16) unsigned short sB[256 * 64];

  if (blockIdx.x < gblk) {
    // ---- out = x @ W0   (K=256, proven body, fp32 store) ----
    const int m0 = blockIdx.x * 128;
    const int tid = threadIdx.x;
    const int w = tid >> 6, l = tid & 63;
    const int lrow = l >> 3, lslot = l & 7;
    const int wr = w >> 2, wc = w & 3;

    f32x4 acc[4][4] = {};

    for (int k0 = 0; k0 < 256; k0 += 64) {
      const unsigned short* Ap = xb;
      const unsigned short* Bp = wt;  // W0t
      int ks = k0;

#pragma unroll
      for (int i = 0; i < 2; i++) {
        int row = w * 16 + i * 8 + lrow;
        int gr = m0 + row;
        if (gr >= N) gr = N - 1;
        int g = lslot ^ lrow;
        const unsigned short* src = Ap + (size_t)gr * TD + ks + g * 8;
        unsigned short* dst = sA + (w * 16 + i * 8) * 64;
        __builtin_amdgcn_global_load_lds(
            (const __attribute__((address_space(1))) void*)src,
            (__attribute__((address_space(3))) void*)dst, 16, 0, 0);
      }
#pragma unroll
      for (int i = 0; i < 4; i++) {
        int row = w * 32 + i * 8 + lrow;
        int g = lslot ^ lrow;
        const unsigned short* src = Bp + (size_t)row * TD + ks + g * 8;
        unsigned short* dst = sB + (w * 32 + i * 8) * 64;
        __builtin_amdgcn_global_load_lds(
            (const __attribute__((address_space(1))) void*)src,
            (__attribute__((address_space(3))) void*)dst, 16, 0, 0);
      }
      __syncthreads();

#pragma unroll
      for (int kk = 0; kk < 2; kk++) {
        short8 a[4], b[4];
#pragma unroll
        for (int m = 0; m < 4; m++) {
          int row = wr * 64 + m * 16 + (l & 15);
          int slot = (kk * 4 + (l >> 4)) ^ (row & 7);
          a[m] = *reinterpret_cast<const short8*>(&sA[row * 64 + slot * 8]);
        }
#pragma unroll
        for (int n = 0; n < 4; n++) {
          int row = wc * 64 + n * 16 + (l & 15);
          int slot = (kk * 4 + (l >> 4)) ^ (row & 7);
          b[n] = *reinterpret_cast<const short8*>(&sB[row * 64 + slot * 8]);
        }
#pragma unroll
        for (int m = 0; m < 4; m++)
#pragma unroll
          for (int n = 0; n < 4; n++)
            acc[m][n] =
                __builtin_amdgcn_mfma_f32_16x16x32_bf16(a[m], b[n], acc[m][n], 0, 0, 0);
      }
      __syncthreads();
    }

#pragma unroll
    for (int m = 0; m < 4; m++)
#pragma unroll
      for (int n = 0; n < 4; n++)
#pragma unroll
        for (int j = 0; j < 4; j++) {
          int r = m0 + wr * 64 + m * 16 + (l >> 4) * 4 + j;
          if (r < N)
            out[(size_t)r * TD + wc * 64 + n * 16 + (l & 15)] = acc[m][n][j];
        }
    return;
  }

  // ---- fused gather (round-13 form): 8 nodes per block, 1 node per wave ----
  int wid = (blockIdx.x - gblk) * 8 + (threadIdx.x >> 6);
  if (wid >= N) return;
  const int lane = threadIdx.x & 63;
  const int eh = lane >> 5;   // edge half 0/1
  const int sl = lane & 31;   // sub-lane: dims [sl*8, sl*8+8)

  // --- graph 1: agg ---
  {
    int beg = off1[wid], end = off1[wid + 1];
    float acc[8] = {};
    for (int j = beg; j < end; j += 4) {
      int e1 = end - 1;
      int j0 = j + eh, j1 = j + 2 + eh;
      int s0 = csr1[j0 < end ? j0 : e1];
      int s1 = csr1[j1 < end ? j1 : e1];
      float k0 = (j0 < end) ? 1.f : 0.f;
      float k1 = (j1 < end) ? 1.f : 0.f;
      ushort8 r0 = *reinterpret_cast<const ushort8*>(xb + (size_t)s0 * TD + sl * 8);
      ushort8 r1 = *reinterpret_cast<const ushort8*>(xb + (size_t)s1 * TD + sl * 8);
#pragma unroll
      for (int i = 0; i < 8; i++)
        acc[i] += k0 * bf2f(r0[i]) + k1 * bf2f(r1[i]);
    }
#pragma unroll
    for (int i = 0; i < 8; i++) acc[i] += __shfl_xor(acc[i], 32, 64);
    if (eh == 0) {
      ushort8 o;
#pragma unroll
      for (int i = 0; i < 8; i++) o[i] = f2bf(acc[i]);
      *reinterpret_cast<ushort8*>(aggb + (size_t)wid * TD + sl * 8) = o;
    }
  }

  // --- graph 2: t = -sum (q'.x[s]) x[s] ---
  {
    ushort8 qv = *reinterpret_cast<const ushort8*>(qb + (size_t)wid * TD + sl * 8);
    float q[8];
#pragma unroll
    for (int i = 0; i < 8; i++) q[i] = bf2f(qv[i]);
    int beg = off2[wid], end = off2[wid + 1];
    float t[8] = {};
    for (int j = beg; j < end; j += 4) {
      int e1 = end - 1;
      int j0 = j + eh, j1 = j + 2 + eh;
      int s0 = csr2[j0 < end ? j0 : e1];
      int s1 = csr2[j1 < end ? j1 : e1];
      float k0 = (j0 < end) ? 1.f : 0.f;
      float k1 = (j1 < end) ? 1.f : 0.f;
      ushort8 r0 = *reinterpret_cast<const ushort8*>(xb + (size_t)s0 * TD + sl * 8);
      ushort8 r1 = *reinterpret_cast<const ushort8*>(xb + (size_t)s1 * TD + sl * 8);
      float x0[8], x1[8];
      float p0 = 0.f, p1 = 0.f;
#pragma unroll
      for (int i = 0; i < 8; i++) {
        x0[i] = bf2f(r0[i]); x1[i] = bf2f(r1[i]);
        p0 += q[i] * x0[i];  p1 += q[i] * x1[i];
      }
#pragma unroll
      for (int m = 1; m < 32; m <<= 1) {
        p0 += __shfl_xor(p0, m, 64);
        p1 += __shfl_xor(p1, m, 64);
      }
      p0 *= k0; p1 *= k1;
#pragma unroll
      for (int i = 0; i < 8; i++) t[i] -= p0 * x0[i] + p1 * x1[i];
    }
#pragma unroll
    for (int i = 0; i < 8; i++) t[i] += __shfl_xor(t[i], 32, 64);
    if (eh == 0) {
      ushort8 o;
#pragma unroll
      for (int i = 0; i < 8; i++) o[i] = f2bf(t[i]);
      *reinterpret_cast<ushort8*>(tb + (size_t)wid * TD + sl * 8) = o;
    }
  }
}

// ===========================================================================
// Final accumulate GEMM: out += aggb@W1 + tb@Wv   (K=512 segmented, fp32 RMW)
// Proven KSTEP=64 / XOR-(row&7) body.
// ===========================================================================
__global__ __launch_bounds__(512) void gemm1_kernel(
    const unsigned short* __restrict__ aggb, const unsigned short* __restrict__ tb,
    const unsigned short* __restrict__ wt, float* __restrict__ out, int M) {
  __shared__ __align__(16) unsigned short sA[128 * 64];
  __shared__ __align__(16) unsigned short sB[256 * 64];

  const int m0 = blockIdx.x * 128;
  const int tid = threadIdx.x;
  const int w = tid >> 6, l = tid & 63;
  const int lrow = l >> 3, lslot = l & 7;
  const int wr = w >> 2, wc = w & 3;

  f32x4 acc[4][4] = {};

  for (int k0 = 0; k0 < 512; k0 += 64) {
    int seg = k0 >> 8;  // 0: agg@W1, 1: t@Wv
    const unsigned short* Ap = seg == 0 ? aggb : tb;
    const unsigned short* Bp = wt + (seg + 1) * 65536;  // W1t, Wvt
    int ks = k0 & 255;

#pragma unroll
    for (int i = 0; i < 2; i++) {
      int row = w * 16 + i * 8 + lrow;
      int gr = m0 + row;
      if (gr >= M) gr = M - 1;
      int g = lslot ^ lrow;
      const unsigned short* src = Ap + (size_t)gr * TD + ks + g * 8;
      unsigned short* dst = sA + (w * 16 + i * 8) * 64;
      __builtin_amdgcn_global_load_lds(
          (const __attribute__((address_space(1))) void*)src,
          (__attribute__((address_space(3))) void*)dst, 16, 0, 0);
    }
#pragma unroll
    for (int i = 0; i < 4; i++) {
      int row = w * 32 + i * 8 + lrow;
      int g = lslot ^ lrow;
      const unsigned short* src = Bp + (size_t)row * TD + ks + g * 8;
      unsigned short* dst = sB + (w * 32 + i * 8) * 64;
      __builtin_amdgcn_global_load_lds(
          (const __attribute__((address_space(1))) void*)src,
          (__attribute__((address_space(3))) void*)dst, 16, 0, 0);
    }
    __syncthreads();

#pragma unroll
    for (int kk = 0; kk < 2; kk++) {
      short8 a[4], b[4];
#pragma unroll
      for (int m = 0; m < 4; m++) {
        int row = wr * 64 + m * 16 + (l & 15);
        int slot = (kk * 4 + (l >> 4)) ^ (row & 7);
        a[m] = *reinterpret_cast<const short8*>(&sA[row * 64 + slot * 8]);
      }
#pragma unroll
      for (int n = 0; n < 4; n++) {
        int row = wc * 64 + n * 16 + (l & 15);
        int slot = (kk * 4 + (l >> 4)) ^ (row & 7);
        b[n] = *reinterpret_cast<const short8*>(&sB[row * 64 + slot * 8]);
      }
#pragma unroll
      for (int m = 0; m < 4; m++)
#pragma unroll
        for (int n = 0; n < 4; n++)
          acc[m][n] =
              __builtin_amdgcn_mfma_f32_16x16x32_bf16(a[m], b[n], acc[m][n], 0, 0, 0);
    }
    __syncthreads();
  }

#pragma unroll
  for (int m = 0; m < 4; m++)
#pragma unroll
    for (int n = 0; n < 4; n++)
#pragma unroll
      for (int j = 0; j < 4; j++) {
        int r = m0 + wr * 64 + m * 16 + (l >> 4) * 4 + j;
        if (r < M) {
          size_t idx = (size_t)r * TD + wc * 64 + n * 16 + (l & 15);
          out[idx] = out[idx] + acc[m][n][j];
        }
      }
}

// ===========================================================================
extern "C" void kernel_launch(void* const* d_in, const int* in_sizes, int n_in,
                              void* d_out, int out_size, void* d_ws,
                              size_t ws_size, hipStream_t stream) {
  const float* x  = (const float*)d_in[0];
  const int*   ei  = (const int*)d_in[1];
  const int*   ei2 = (const int*)d_in[2];
  const float* W0 = (const float*)d_in[3];
  const float* W1 = (const float*)d_in[4];
  const float* Wq = (const float*)d_in[5];
  const float* Wk = (const float*)d_in[6];
  const float* Wv = (const float*)d_in[7];

  const int N  = in_sizes[0] / TD;
  const int E1 = in_sizes[1] / 2;
  const int E2 = in_sizes[2] / 2;

  float* out = (float*)d_out;
  const size_t rowN = (size_t)N * TD;

  // ---- workspace layout ----
  char* p = (char*)d_ws;
  unsigned short* xb   = (unsigned short*)p; p += rowN * 2;
  unsigned short* aggb = (unsigned short*)p; p += rowN * 2;
  unsigned short* qb   = (unsigned short*)p; p += rowN * 2;
  unsigned short* tb   = (unsigned short*)p; p += rowN * 2;
  unsigned short* wt   = (unsigned short*)p; p += 3 * 65536 * 2;  // W0t,W1t,Wvt
  unsigned short* gt   = (unsigned short*)p; p += 65536 * 2;
  unsigned short* wqb  = (unsigned short*)p; p += 65536 * 2;
  unsigned short* wkb  = (unsigned short*)p; p += 65536 * 2;
  int* off1 = (int*)p; p += (N + 1) * 4;
  int* cur1 = (int*)p; p += N * 4;
  int* off2 = (int*)p; p += (N + 1) * 4;
  int* cur2 = (int*)p; p += N * 4;
  int* csr1 = (int*)p; p += (size_t)E1 * 4;
  int* csr2 = (int*)p; p += (size_t)E2 * 4;
  int* deg1 = (int*)p; p += N * 4;
  int* deg2 = (int*)p; p += N * 4;
  int* bsum = (int*)p; p += 512 * 4;

  // 1. zero degree arrays
  hipMemsetAsync(deg1, 0, (size_t)2 * N * sizeof(int), stream);

  // 2. prologue: hist + all dtype conversions in one dispatch
  long total8 = rowN / 8;
  int nbH = 512;
  int nbX = (int)((total8 + 255) / 256);
  prologue_kernel<<<nbH + nbX + 64 + 768, 256, 0, stream>>>(
      ei, E1, ei2, E2, deg1, deg2, x, xb, total8, Wq, Wk, wqb, wkb, W0, W1, Wv,
      wt, nbH, nbX);

  // 3. scan phase A + G = Wq@Wk^T, then fused prefix+fill of off/cur
  scanA_gemmG_kernel<<<516, 256, 0, stream>>>(deg1, deg2, N, bsum, wqb, wkb, gt);
  scan_fill_kernel<<<512, 256, 0, stream>>>(deg1, deg2, bsum, N, off1, cur1,
                                            off2, cur2);

  // 4. CSR fill  ||  q' = x @ G
  int gblk = (N + 127) / 128;
  int FB = 384;
  fill_gemm0_kernel<<<FB + gblk, 512, 0, stream>>>(
      ei, E1, ei2, E2, cur1, cur2, csr1, csr2, xb, gt, qb, N, FB);

  // 5. out = x@W0 (MFMA)  ||  fused gather (VALU/mem)  -- one dispatch
  int GB = (N + 7) / 8;
  gather_xw0_kernel<<<gblk + GB, 512, 0, stream>>>(
      xb, qb, off1, csr1, off2, csr2, N, aggb, tb, wt, out, gblk);

  // 6. out += agg@W1 + t@Wv
  gemm1_kernel<<<gblk, 512, 0, stream>>>(aggb, tb, wt, out, N);
}

// Round 15
// 197.823 us; speedup vs baseline: 1.1495x; 1.1495x over previous
//
#include <hip/hip_runtime.h>

#define TD 256  // feature dim

typedef __attribute__((ext_vector_type(8))) short short8;
typedef __attribute__((ext_vector_type(8))) unsigned short ushort8;
typedef __attribute__((ext_vector_type(4))) float f32x4;

__device__ inline unsigned short f2bf(float f) {
  unsigned u = __float_as_uint(f);
  u = u + 0x7fffu + ((u >> 16) & 1u);  // round-to-nearest-even
  return (unsigned short)(u >> 16);
}
__device__ inline float bf2f(unsigned short h) {
  return __uint_as_float(((unsigned)h) << 16);
}

// ===========================================================================
// Prologue mega-kernel: hist | x->bf16 | Wq,Wk row-major bf16 | W0,W1,Wv^T bf16
// ===========================================================================
__global__ __launch_bounds__(256) void prologue_kernel(
    const int* __restrict__ ei, int E1, const int* __restrict__ ei2, int E2,
    int* __restrict__ deg1, int* __restrict__ deg2,
    const float* __restrict__ x, unsigned short* __restrict__ xb, long total8,
    const float* __restrict__ Wq, const float* __restrict__ Wk,
    unsigned short* __restrict__ wqb, unsigned short* __restrict__ wkb,
    const float* __restrict__ W0, const float* __restrict__ W1,
    const float* __restrict__ Wv, unsigned short* __restrict__ wt,
    int nbH, int nbX) {
  int b = blockIdx.x;
  if (b < nbH) {
    int stride = nbH * 256;
    int Emax = max(E1, E2);
    for (int i = b * 256 + threadIdx.x; i < Emax; i += stride) {
      if (i < E1) atomicAdd(&deg1[ei[E1 + i]], 1);
      if (i < E2) atomicAdd(&deg2[ei2[E2 + i]], 1);
    }
  } else if (b < nbH + nbX) {
    long t = (long)(b - nbH) * 256 + threadIdx.x;
    if (t >= total8) return;
    const float4 f0 = *reinterpret_cast<const float4*>(x + t * 8);
    const float4 f1 = *reinterpret_cast<const float4*>(x + t * 8 + 4);
    ushort8 o;
    o[0] = f2bf(f0.x); o[1] = f2bf(f0.y); o[2] = f2bf(f0.z); o[3] = f2bf(f0.w);
    o[4] = f2bf(f1.x); o[5] = f2bf(f1.y); o[6] = f2bf(f1.z); o[7] = f2bf(f1.w);
    *reinterpret_cast<ushort8*>(xb + t * 8) = o;
  } else if (b < nbH + nbX + 64) {
    int t = (b - nbH - nbX) * 256 + threadIdx.x;  // 0..16383
    const float* src = (t < 8192) ? Wq : Wk;
    unsigned short* dst = (t < 8192) ? wqb : wkb;
    int o = (t & 8191) * 8;
    ushort8 r;
#pragma unroll
    for (int j = 0; j < 8; j++) r[j] = f2bf(src[o + j]);
    *reinterpret_cast<ushort8*>(dst + o) = r;
  } else {
    int b2 = b - nbH - nbX - 64;  // 0..767
    int m = b2 >> 8;
    int n = b2 & 255;
    int k = threadIdx.x;
    const float* W = m == 0 ? W0 : m == 1 ? W1 : Wv;
    wt[m * 65536 + n * 256 + k] = f2bf(W[k * 256 + n]);
  }
}

// ===========================================================================
// scan phase A (blocks 0..511) + gemmG (blocks 512..515)
// ===========================================================================
__global__ __launch_bounds__(256) void scanA_gemmG_kernel(
    const int* __restrict__ deg1, const int* __restrict__ deg2, int N,
    int* __restrict__ bsum,
    const unsigned short* __restrict__ wqb, const unsigned short* __restrict__ wkb,
    unsigned short* __restrict__ gt) {
  if (blockIdx.x < 512) {
    int arr = blockIdx.x >> 8;
    int b = blockIdx.x & 255;
    const int* deg = arr ? deg2 : deg1;
    int i = b * 256 + threadIdx.x;
    int v = (i < N) ? deg[i] : 0;
#pragma unroll
    for (int m = 1; m < 64; m <<= 1) v += __shfl_xor(v, m, 64);
    __shared__ int wsum[4];
    if ((threadIdx.x & 63) == 0) wsum[threadIdx.x >> 6] = v;
    __syncthreads();
    if (threadIdx.x == 0)
      bsum[blockIdx.x] = wsum[0] + wsum[1] + wsum[2] + wsum[3];
    return;
  }
  const int t = (blockIdx.x - 512) * 4 + (threadIdx.x >> 6);
  const int l = threadIdx.x & 63;
  const int a0 = (t >> 2) * 64;
  const int b0 = (t & 3) * 64;
  const int lc = l & 15;
  const int lk = l >> 4;
  f32x4 acc[4][4] = {};
#pragma unroll
  for (int ks = 0; ks < 256; ks += 32) {
    const int ko = ks + lk * 8;
    short8 a[4], b[4];
#pragma unroll
    for (int m = 0; m < 4; m++)
      a[m] = *reinterpret_cast<const short8*>(wqb + (a0 + m * 16 + lc) * 256 + ko);
#pragma unroll
    for (int n = 0; n < 4; n++)
      b[n] = *reinterpret_cast<const short8*>(wkb + (b0 + n * 16 + lc) * 256 + ko);
#pragma unroll
    for (int m = 0; m < 4; m++)
#pragma unroll
      for (int n = 0; n < 4; n++)
        acc[m][n] =
            __builtin_amdgcn_mfma_f32_16x16x32_bf16(a[m], b[n], acc[m][n], 0, 0, 0);
  }
#pragma unroll
  for (int m = 0; m < 4; m++)
#pragma unroll
    for (int n = 0; n < 4; n++)
#pragma unroll
      for (int j = 0; j < 4; j++) {
        int a = a0 + m * 16 + lk * 4 + j;
        int b = b0 + n * 16 + lc;
        gt[b * 256 + a] = f2bf(acc[m][n][j]);
      }
}

// ===========================================================================
// scan_fill with in-block bsum prefix.  grid = 512.  bsum = RAW block sums.
// ===========================================================================
__global__ __launch_bounds__(256) void scan_fill_kernel(
    const int* __restrict__ deg1, const int* __restrict__ deg2,
    const int* __restrict__ bsum, int N,
    int* __restrict__ off1, int* __restrict__ cur1,
    int* __restrict__ off2, int* __restrict__ cur2) {
  int arr = blockIdx.x >> 8;
  int b = blockIdx.x & 255;
  const int* deg = arr ? deg2 : deg1;
  int* off = arr ? off2 : off1;
  int* cur = arr ? cur2 : cur1;
  const int t = threadIdx.x;

  __shared__ int redp[4], redt[4];
  int sval = bsum[arr * 256 + t];
  int pv = (t < b) ? sval : 0;
  int tv = sval;
#pragma unroll
  for (int m = 1; m < 64; m <<= 1) {
    pv += __shfl_xor(pv, m, 64);
    tv += __shfl_xor(tv, m, 64);
  }
  if ((t & 63) == 0) { redp[t >> 6] = pv; redt[t >> 6] = tv; }
  __syncthreads();
  int prefix = redp[0] + redp[1] + redp[2] + redp[3];
  int total = redt[0] + redt[1] + redt[2] + redt[3];
  if (b == 255 && t == 0) off[N] = total;

  int i = b * 256 + t;
  __shared__ int sm[256];
  int v = (i < N) ? deg[i] : 0;
  sm[t] = v;
  __syncthreads();
  for (int d = 1; d < 256; d <<= 1) {
    int val = (t >= d) ? sm[t - d] : 0;
    __syncthreads();
    sm[t] += val;
    __syncthreads();
  }
  int e = sm[t] - v + prefix;
  if (i < N) {
    off[i] = e;
    cur[i] = e;
  }
}

// ===========================================================================
// GEMM tile body (round-5-proven): 128x256, 512 thr, KSTEP=64, XOR-(row&7).
// Computes acc for A[M,256]-panel rows m0.., B = Bp (256x256 transposed).
// ===========================================================================
__device__ __forceinline__ void gemm_tile_k256(
    const unsigned short* __restrict__ Ap, const unsigned short* __restrict__ Bp,
    int m0, int M, unsigned short* sA, unsigned short* sB, f32x4 (&acc)[4][4]) {
  const int tid = threadIdx.x;
  const int w = tid >> 6, l = tid & 63;
  const int lrow = l >> 3, lslot = l & 7;
  const int wr = w >> 2, wc = w & 3;

  for (int k0 = 0; k0 < 256; k0 += 64) {
#pragma unroll
    for (int i = 0; i < 2; i++) {
      int row = w * 16 + i * 8 + lrow;
      int gr = m0 + row;
      if (gr >= M) gr = M - 1;
      int g = lslot ^ lrow;
      const unsigned short* src = Ap + (size_t)gr * TD + k0 + g * 8;
      unsigned short* dst = sA + (w * 16 + i * 8) * 64;
      __builtin_amdgcn_global_load_lds(
          (const __attribute__((address_space(1))) void*)src,
          (__attribute__((address_space(3))) void*)dst, 16, 0, 0);
    }
#pragma unroll
    for (int i = 0; i < 4; i++) {
      int row = w * 32 + i * 8 + lrow;
      int g = lslot ^ lrow;
      const unsigned short* src = Bp + (size_t)row * TD + k0 + g * 8;
      unsigned short* dst = sB + (w * 32 + i * 8) * 64;
      __builtin_amdgcn_global_load_lds(
          (const __attribute__((address_space(1))) void*)src,
          (__attribute__((address_space(3))) void*)dst, 16, 0, 0);
    }
    __syncthreads();

#pragma unroll
    for (int kk = 0; kk < 2; kk++) {
      short8 a[4], b[4];
#pragma unroll
      for (int m = 0; m < 4; m++) {
        int row = wr * 64 + m * 16 + (l & 15);
        int slot = (kk * 4 + (l >> 4)) ^ (row & 7);
        a[m] = *reinterpret_cast<const short8*>(&sA[row * 64 + slot * 8]);
      }
#pragma unroll
      for (int n = 0; n < 4; n++) {
        int row = wc * 64 + n * 16 + (l & 15);
        int slot = (kk * 4 + (l >> 4)) ^ (row & 7);
        b[n] = *reinterpret_cast<const short8*>(&sB[row * 64 + slot * 8]);
      }
#pragma unroll
      for (int m = 0; m < 4; m++)
#pragma unroll
        for (int n = 0; n < 4; n++)
          acc[m][n] =
              __builtin_amdgcn_mfma_f32_16x16x32_bf16(a[m], b[n], acc[m][n], 0, 0, 0);
    }
    __syncthreads();
  }
}

// ===========================================================================
// Dispatch 4: blocks [0,FB) CSR fill; [FB,FB+gblk) q'=x@Gt (bf16 out);
// [FB+gblk, FB+2*gblk) out=x@W0 (fp32 out).  All GEMM-shaped -> shared LDS ok.
// ===========================================================================
__global__ __launch_bounds__(512) void fill_gemm0_kernel(
    const int* __restrict__ ei, int E1, const int* __restrict__ ei2, int E2,
    int* __restrict__ cur1, int* __restrict__ cur2,
    int* __restrict__ csr1, int* __restrict__ csr2,
    const unsigned short* __restrict__ xb, const unsigned short* __restrict__ gt,
    const unsigned short* __restrict__ wt,
    unsigned short* __restrict__ qb, float* __restrict__ out, int M, int FB,
    int gblk) {
  __shared__ __align__(16) unsigned short sA[128 * 64];
  __shared__ __align__(16) unsigned short sB[256 * 64];

  if (blockIdx.x < FB) {
    int stride = FB * 512;
    int Emax = max(E1, E2);
    for (int i = blockIdx.x * 512 + threadIdx.x; i < Emax; i += stride) {
      if (i < E1) {
        int d = ei[E1 + i];
        int p = atomicAdd(&cur1[d], 1);
        csr1[p] = ei[i];
      }
      if (i < E2) {
        int d = ei2[E2 + i];
        int p = atomicAdd(&cur2[d], 1);
        csr2[p] = ei2[i];
      }
    }
    return;
  }

  const int gb = blockIdx.x - FB;
  const bool isQ = gb < gblk;
  const int m0 = (isQ ? gb : gb - gblk) * 128;
  f32x4 acc[4][4] = {};
  gemm_tile_k256(xb, isQ ? gt : wt, m0, M, sA, sB, acc);

  const int l = threadIdx.x & 63;
  const int w = threadIdx.x >> 6;
  const int wr = w >> 2, wc = w & 3;
  if (isQ) {
#pragma unroll
    for (int m = 0; m < 4; m++)
#pragma unroll
      for (int n = 0; n < 4; n++)
#pragma unroll
        for (int j = 0; j < 4; j++) {
          int r = m0 + wr * 64 + m * 16 + (l >> 4) * 4 + j;
          if (r < M)
            qb[(size_t)r * TD + wc * 64 + n * 16 + (l & 15)] = f2bf(acc[m][n][j]);
        }
  } else {
#pragma unroll
    for (int m = 0; m < 4; m++)
#pragma unroll
      for (int n = 0; n < 4; n++)
#pragma unroll
        for (int j = 0; j < 4; j++) {
          int r = m0 + wr * 64 + m * 16 + (l >> 4) * 4 + j;
          if (r < M)
            out[(size_t)r * TD + wc * 64 + n * 16 + (l & 15)] = acc[m][n][j];
        }
  }
}

// ===========================================================================
// Fused gather (round-13-proven): one wave per node; 2 edges via 32-lane
// halves; 16B/lane; 2-wide batch -> 4 edges in flight.
// ===========================================================================
__global__ __launch_bounds__(256) void gather_fused_kernel(
    const unsigned short* __restrict__ xb, const unsigned short* __restrict__ qb,
    const int* __restrict__ off1, const int* __restrict__ csr1,
    const int* __restrict__ off2, const int* __restrict__ csr2,
    int N, unsigned short* __restrict__ aggb, unsigned short* __restrict__ tb) {
  int wid = blockIdx.x * 4 + (threadIdx.x >> 6);
  if (wid >= N) return;
  const int lane = threadIdx.x & 63;
  const int eh = lane >> 5;   // edge half 0/1
  const int sl = lane & 31;   // sub-lane: dims [sl*8, sl*8+8)

  // --- graph 1: agg ---
  {
    int beg = off1[wid], end = off1[wid + 1];
    float acc[8] = {};
    for (int j = beg; j < end; j += 4) {
      int e1 = end - 1;
      int j0 = j + eh, j1 = j + 2 + eh;
      int s0 = csr1[j0 < end ? j0 : e1];
      int s1 = csr1[j1 < end ? j1 : e1];
      float k0 = (j0 < end) ? 1.f : 0.f;
      float k1 = (j1 < end) ? 1.f : 0.f;
      ushort8 r0 = *reinterpret_cast<const ushort8*>(xb + (size_t)s0 * TD + sl * 8);
      ushort8 r1 = *reinterpret_cast<const ushort8*>(xb + (size_t)s1 * TD + sl * 8);
#pragma unroll
      for (int i = 0; i < 8; i++)
        acc[i] += k0 * bf2f(r0[i]) + k1 * bf2f(r1[i]);
    }
#pragma unroll
    for (int i = 0; i < 8; i++) acc[i] += __shfl_xor(acc[i], 32, 64);
    if (eh == 0) {
      ushort8 o;
#pragma unroll
      for (int i = 0; i < 8; i++) o[i] = f2bf(acc[i]);
      *reinterpret_cast<ushort8*>(aggb + (size_t)wid * TD + sl * 8) = o;
    }
  }

  // --- graph 2: t = -sum (q'.x[s]) x[s] ---
  {
    ushort8 qv = *reinterpret_cast<const ushort8*>(qb + (size_t)wid * TD + sl * 8);
    float q[8];
#pragma unroll
    for (int i = 0; i < 8; i++) q[i] = bf2f(qv[i]);
    int beg = off2[wid], end = off2[wid + 1];
    float t[8] = {};
    for (int j = beg; j < end; j += 4) {
      int e1 = end - 1;
      int j0 = j + eh, j1 = j + 2 + eh;
      int s0 = csr2[j0 < end ? j0 : e1];
      int s1 = csr2[j1 < end ? j1 : e1];
      float k0 = (j0 < end) ? 1.f : 0.f;
      float k1 = (j1 < end) ? 1.f : 0.f;
      ushort8 r0 = *reinterpret_cast<const ushort8*>(xb + (size_t)s0 * TD + sl * 8);
      ushort8 r1 = *reinterpret_cast<const ushort8*>(xb + (size_t)s1 * TD + sl * 8);
      float x0[8], x1[8];
      float p0 = 0.f, p1 = 0.f;
#pragma unroll
      for (int i = 0; i < 8; i++) {
        x0[i] = bf2f(r0[i]); x1[i] = bf2f(r1[i]);
        p0 += q[i] * x0[i];  p1 += q[i] * x1[i];
      }
#pragma unroll
      for (int m = 1; m < 32; m <<= 1) {
        p0 += __shfl_xor(p0, m, 64);
        p1 += __shfl_xor(p1, m, 64);
      }
      p0 *= k0; p1 *= k1;
#pragma unroll
      for (int i = 0; i < 8; i++) t[i] -= p0 * x0[i] + p1 * x1[i];
    }
#pragma unroll
    for (int i = 0; i < 8; i++) t[i] += __shfl_xor(t[i], 32, 64);
    if (eh == 0) {
      ushort8 o;
#pragma unroll
      for (int i = 0; i < 8; i++) o[i] = f2bf(t[i]);
      *reinterpret_cast<ushort8*>(tb + (size_t)wid * TD + sl * 8) = o;
    }
  }
}

// ===========================================================================
// Final accumulate GEMM: out += aggb@W1 + tb@Wv  (K=512 segmented, fp32 RMW)
// Proven KSTEP=64 / XOR-(row&7) body (round-14-verified).
// ===========================================================================
__global__ __launch_bounds__(512) void gemm1_kernel(
    const unsigned short* __restrict__ aggb, const unsigned short* __restrict__ tb,
    const unsigned short* __restrict__ wt, float* __restrict__ out, int M) {
  __shared__ __align__(16) unsigned short sA[128 * 64];
  __shared__ __align__(16) unsigned short sB[256 * 64];

  const int m0 = blockIdx.x * 128;
  const int tid = threadIdx.x;
  const int w = tid >> 6, l = tid & 63;
  const int lrow = l >> 3, lslot = l & 7;
  const int wr = w >> 2, wc = w & 3;

  f32x4 acc[4][4] = {};

  for (int k0 = 0; k0 < 512; k0 += 64) {
    int seg = k0 >> 8;  // 0: agg@W1, 1: t@Wv
    const unsigned short* Ap = seg == 0 ? aggb : tb;
    const unsigned short* Bp = wt + (seg + 1) * 65536;  // W1t, Wvt
    int ks = k0 & 255;

#pragma unroll
    for (int i = 0; i < 2; i++) {
      int row = w * 16 + i * 8 + lrow;
      int gr = m0 + row;
      if (gr >= M) gr = M - 1;
      int g = lslot ^ lrow;
      const unsigned short* src = Ap + (size_t)gr * TD + ks + g * 8;
      unsigned short* dst = sA + (w * 16 + i * 8) * 64;
      __builtin_amdgcn_global_load_lds(
          (const __attribute__((address_space(1))) void*)src,
          (__attribute__((address_space(3))) void*)dst, 16, 0, 0);
    }
#pragma unroll
    for (int i = 0; i < 4; i++) {
      int row = w * 32 + i * 8 + lrow;
      int g = lslot ^ lrow;
      const unsigned short* src = Bp + (size_t)row * TD + ks + g * 8;
      unsigned short* dst = sB + (w * 32 + i * 8) * 64;
      __builtin_amdgcn_global_load_lds(
          (const __attribute__((address_space(1))) void*)src,
          (__attribute__((address_space(3))) void*)dst, 16, 0, 0);
    }
    __syncthreads();

#pragma unroll
    for (int kk = 0; kk < 2; kk++) {
      short8 a[4], b[4];
#pragma unroll
      for (int m = 0; m < 4; m++) {
        int row = wr * 64 + m * 16 + (l & 15);
        int slot = (kk * 4 + (l >> 4)) ^ (row & 7);
        a[m] = *reinterpret_cast<const short8*>(&sA[row * 64 + slot * 8]);
      }
#pragma unroll
      for (int n = 0; n < 4; n++) {
        int row = wc * 64 + n * 16 + (l & 15);
        int slot = (kk * 4 + (l >> 4)) ^ (row & 7);
        b[n] = *reinterpret_cast<const short8*>(&sB[row * 64 + slot * 8]);
      }
#pragma unroll
      for (int m = 0; m < 4; m++)
#pragma unroll
        for (int n = 0; n < 4; n++)
          acc[m][n] =
              __builtin_amdgcn_mfma_f32_16x16x32_bf16(a[m], b[n], acc[m][n], 0, 0, 0);
    }
    __syncthreads();
  }

#pragma unroll
  for (int m = 0; m < 4; m++)
#pragma unroll
    for (int n = 0; n < 4; n++)
#pragma unroll
      for (int j = 0; j < 4; j++) {
        int r = m0 + wr * 64 + m * 16 + (l >> 4) * 4 + j;
        if (r < M) {
          size_t idx = (size_t)r * TD + wc * 64 + n * 16 + (l & 15);
          out[idx] = out[idx] + acc[m][n][j];
        }
      }
}

// ===========================================================================
extern "C" void kernel_launch(void* const* d_in, const int* in_sizes, int n_in,
                              void* d_out, int out_size, void* d_ws,
                              size_t ws_size, hipStream_t stream) {
  const float* x  = (const float*)d_in[0];
  const int*   ei  = (const int*)d_in[1];
  const int*   ei2 = (const int*)d_in[2];
  const float* W0 = (const float*)d_in[3];
  const float* W1 = (const float*)d_in[4];
  const float* Wq = (const float*)d_in[5];
  const float* Wk = (const float*)d_in[6];
  const float* Wv = (const float*)d_in[7];

  const int N  = in_sizes[0] / TD;
  const int E1 = in_sizes[1] / 2;
  const int E2 = in_sizes[2] / 2;

  float* out = (float*)d_out;
  const size_t rowN = (size_t)N * TD;

  // ---- workspace layout ----
  char* p = (char*)d_ws;
  unsigned short* xb   = (unsigned short*)p; p += rowN * 2;
  unsigned short* aggb = (unsigned short*)p; p += rowN * 2;
  unsigned short* qb   = (unsigned short*)p; p += rowN * 2;
  unsigned short* tb   = (unsigned short*)p; p += rowN * 2;
  unsigned short* wt   = (unsigned short*)p; p += 3 * 65536 * 2;  // W0t,W1t,Wvt
  unsigned short* gt   = (unsigned short*)p; p += 65536 * 2;
  unsigned short* wqb  = (unsigned short*)p; p += 65536 * 2;
  unsigned short* wkb  = (unsigned short*)p; p += 65536 * 2;
  int* off1 = (int*)p; p += (N + 1) * 4;
  int* cur1 = (int*)p; p += N * 4;
  int* off2 = (int*)p; p += (N + 1) * 4;
  int* cur2 = (int*)p; p += N * 4;
  int* csr1 = (int*)p; p += (size_t)E1 * 4;
  int* csr2 = (int*)p; p += (size_t)E2 * 4;
  int* deg1 = (int*)p; p += N * 4;
  int* deg2 = (int*)p; p += N * 4;
  int* bsum = (int*)p; p += 512 * 4;

  // 1. zero degree arrays
  hipMemsetAsync(deg1, 0, (size_t)2 * N * sizeof(int), stream);

  // 2. prologue: hist + all dtype conversions in one dispatch
  long total8 = rowN / 8;
  int nbH = 512;
  int nbX = (int)((total8 + 255) / 256);
  prologue_kernel<<<nbH + nbX + 64 + 768, 256, 0, stream>>>(
      ei, E1, ei2, E2, deg1, deg2, x, xb, total8, Wq, Wk, wqb, wkb, W0, W1, Wv,
      wt, nbH, nbX);

  // 3. scan phase A + G = Wq@Wk^T, then fused prefix+fill of off/cur
  scanA_gemmG_kernel<<<516, 256, 0, stream>>>(deg1, deg2, N, bsum, wqb, wkb, gt);
  scan_fill_kernel<<<512, 256, 0, stream>>>(deg1, deg2, bsum, N, off1, cur1,
                                            off2, cur2);

  // 4. CSR fill || q'=x@G || out=x@W0   (all GEMM-shaped or LDS-tolerant)
  int gblk = (N + 127) / 128;
  int FB = 384;
  fill_gemm0_kernel<<<FB + 2 * gblk, 512, 0, stream>>>(
      ei, E1, ei2, E2, cur1, cur2, csr1, csr2, xb, gt, wt, qb, out, N, FB, gblk);

  // 5. fused gather (proven standalone form)
  gather_fused_kernel<<<(N + 3) / 4, 256, 0, stream>>>(xb, qb, off1, csr1,
                                                       off2, csr2, N, aggb, tb);

  // 6. out += agg@W1 + t@Wv
  gemm1_kernel<<<gblk, 512, 0, stream>>>(aggb, tb, wt, out, N);
}

// Round 17
// 177.459 us; speedup vs baseline: 1.2815x; 1.1148x over previous
//
#include <hip/hip_runtime.h>

#define TD 256  // feature dim

typedef __attribute__((ext_vector_type(8))) short short8;
typedef __attribute__((ext_vector_type(8))) unsigned short ushort8;
typedef __attribute__((ext_vector_type(4))) float f32x4;

__device__ inline unsigned short f2bf(float f) {
  unsigned u = __float_as_uint(f);
  u = u + 0x7fffu + ((u >> 16) & 1u);  // round-to-nearest-even
  return (unsigned short)(u >> 16);
}
__device__ inline float bf2f(unsigned short h) {
  return __uint_as_float(((unsigned)h) << 16);
}

// ===========================================================================
// Prologue mega-kernel: hist | x->bf16 | Wq,Wk row-major bf16 | W0,W1,Wv^T bf16
// ===========================================================================
__global__ __launch_bounds__(256) void prologue_kernel(
    const int* __restrict__ ei, int E1, const int* __restrict__ ei2, int E2,
    int* __restrict__ deg1, int* __restrict__ deg2,
    const float* __restrict__ x, unsigned short* __restrict__ xb, long total8,
    const float* __restrict__ Wq, const float* __restrict__ Wk,
    unsigned short* __restrict__ wqb, unsigned short* __restrict__ wkb,
    const float* __restrict__ W0, const float* __restrict__ W1,
    const float* __restrict__ Wv, unsigned short* __restrict__ wt,
    int nbH, int nbX) {
  int b = blockIdx.x;
  if (b < nbH) {
    int stride = nbH * 256;
    int Emax = max(E1, E2);
    for (int i = b * 256 + threadIdx.x; i < Emax; i += stride) {
      if (i < E1) atomicAdd(&deg1[ei[E1 + i]], 1);
      if (i < E2) atomicAdd(&deg2[ei2[E2 + i]], 1);
    }
  } else if (b < nbH + nbX) {
    long t = (long)(b - nbH) * 256 + threadIdx.x;
    if (t >= total8) return;
    const float4 f0 = *reinterpret_cast<const float4*>(x + t * 8);
    const float4 f1 = *reinterpret_cast<const float4*>(x + t * 8 + 4);
    ushort8 o;
    o[0] = f2bf(f0.x); o[1] = f2bf(f0.y); o[2] = f2bf(f0.z); o[3] = f2bf(f0.w);
    o[4] = f2bf(f1.x); o[5] = f2bf(f1.y); o[6] = f2bf(f1.z); o[7] = f2bf(f1.w);
    *reinterpret_cast<ushort8*>(xb + t * 8) = o;
  } else if (b < nbH + nbX + 64) {
    int t = (b - nbH - nbX) * 256 + threadIdx.x;  // 0..16383
    const float* src = (t < 8192) ? Wq : Wk;
    unsigned short* dst = (t < 8192) ? wqb : wkb;
    int o = (t & 8191) * 8;
    ushort8 r;
#pragma unroll
    for (int j = 0; j < 8; j++) r[j] = f2bf(src[o + j]);
    *reinterpret_cast<ushort8*>(dst + o) = r;
  } else {
    int b2 = b - nbH - nbX - 64;  // 0..767
    int m = b2 >> 8;
    int n = b2 & 255;
    int k = threadIdx.x;
    const float* W = m == 0 ? W0 : m == 1 ? W1 : Wv;
    wt[m * 65536 + n * 256 + k] = f2bf(W[k * 256 + n]);
  }
}

// ===========================================================================
// scan phase A (blocks 0..511) + gemmG (blocks 512..515)
// ===========================================================================
__global__ __launch_bounds__(256) void scanA_gemmG_kernel(
    const int* __restrict__ deg1, const int* __restrict__ deg2, int N,
    int* __restrict__ bsum,
    const unsigned short* __restrict__ wqb, const unsigned short* __restrict__ wkb,
    unsigned short* __restrict__ gt) {
  if (blockIdx.x < 512) {
    int arr = blockIdx.x >> 8;
    int b = blockIdx.x & 255;
    const int* deg = arr ? deg2 : deg1;
    int i = b * 256 + threadIdx.x;
    int v = (i < N) ? deg[i] : 0;
#pragma unroll
    for (int m = 1; m < 64; m <<= 1) v += __shfl_xor(v, m, 64);
    __shared__ int wsum[4];
    if ((threadIdx.x & 63) == 0) wsum[threadIdx.x >> 6] = v;
    __syncthreads();
    if (threadIdx.x == 0)
      bsum[blockIdx.x] = wsum[0] + wsum[1] + wsum[2] + wsum[3];
    return;
  }
  const int t = (blockIdx.x - 512) * 4 + (threadIdx.x >> 6);
  const int l = threadIdx.x & 63;
  const int a0 = (t >> 2) * 64;
  const int b0 = (t & 3) * 64;
  const int lc = l & 15;
  const int lk = l >> 4;
  f32x4 acc[4][4] = {};
#pragma unroll
  for (int ks = 0; ks < 256; ks += 32) {
    const int ko = ks + lk * 8;
    short8 a[4], b[4];
#pragma unroll
    for (int m = 0; m < 4; m++)
      a[m] = *reinterpret_cast<const short8*>(wqb + (a0 + m * 16 + lc) * 256 + ko);
#pragma unroll
    for (int n = 0; n < 4; n++)
      b[n] = *reinterpret_cast<const short8*>(wkb + (b0 + n * 16 + lc) * 256 + ko);
#pragma unroll
    for (int m = 0; m < 4; m++)
#pragma unroll
      for (int n = 0; n < 4; n++)
        acc[m][n] =
            __builtin_amdgcn_mfma_f32_16x16x32_bf16(a[m], b[n], acc[m][n], 0, 0, 0);
  }
#pragma unroll
  for (int m = 0; m < 4; m++)
#pragma unroll
    for (int n = 0; n < 4; n++)
#pragma unroll
      for (int j = 0; j < 4; j++) {
        int a = a0 + m * 16 + lk * 4 + j;
        int b = b0 + n * 16 + lc;
        gt[b * 256 + a] = f2bf(acc[m][n][j]);
      }
}

// ===========================================================================
// scan_fill with in-block bsum prefix.  grid = 512.  bsum = RAW block sums.
// ===========================================================================
__global__ __launch_bounds__(256) void scan_fill_kernel(
    const int* __restrict__ deg1, const int* __restrict__ deg2,
    const int* __restrict__ bsum, int N,
    int* __restrict__ off1, int* __restrict__ cur1,
    int* __restrict__ off2, int* __restrict__ cur2) {
  int arr = blockIdx.x >> 8;
  int b = blockIdx.x & 255;
  const int* deg = arr ? deg2 : deg1;
  int* off = arr ? off2 : off1;
  int* cur = arr ? cur2 : cur1;
  const int t = threadIdx.x;

  __shared__ int redp[4], redt[4];
  int sval = bsum[arr * 256 + t];
  int pv = (t < b) ? sval : 0;
  int tv = sval;
#pragma unroll
  for (int m = 1; m < 64; m <<= 1) {
    pv += __shfl_xor(pv, m, 64);
    tv += __shfl_xor(tv, m, 64);
  }
  if ((t & 63) == 0) { redp[t >> 6] = pv; redt[t >> 6] = tv; }
  __syncthreads();
  int prefix = redp[0] + redp[1] + redp[2] + redp[3];
  int total = redt[0] + redt[1] + redt[2] + redt[3];
  if (b == 255 && t == 0) off[N] = total;

  int i = b * 256 + t;
  __shared__ int sm[256];
  int v = (i < N) ? deg[i] : 0;
  sm[t] = v;
  __syncthreads();
  for (int d = 1; d < 256; d <<= 1) {
    int val = (t >= d) ? sm[t - d] : 0;
    __syncthreads();
    sm[t] += val;
    __syncthreads();
  }
  int e = sm[t] - v + prefix;
  if (i < N) {
    off[i] = e;
    cur[i] = e;
  }
}

// ===========================================================================
// Merged: blocks [0,FB) do CSR fill; blocks [FB, FB+gblk) do gemm0 (q'=x@Gt),
// round-5-proven KSTEP=64 / XOR-(row&7) GEMM body UNCHANGED.
// ===========================================================================
__global__ __launch_bounds__(512) void fill_gemm0_kernel(
    const int* __restrict__ ei, int E1, const int* __restrict__ ei2, int E2,
    int* __restrict__ cur1, int* __restrict__ cur2,
    int* __restrict__ csr1, int* __restrict__ csr2,
    const unsigned short* __restrict__ xb, const unsigned short* __restrict__ gt,
    unsigned short* __restrict__ qb, int M, int FB) {
  __shared__ __align__(16) unsigned short sA[128 * 64];
  __shared__ __align__(16) unsigned short sB[256 * 64];

  if (blockIdx.x < FB) {
    int stride = FB * 512;
    int Emax = max(E1, E2);
    for (int i = blockIdx.x * 512 + threadIdx.x; i < Emax; i += stride) {
      if (i < E1) {
        int d = ei[E1 + i];
        int p = atomicAdd(&cur1[d], 1);
        csr1[p] = ei[i];
      }
      if (i < E2) {
        int d = ei2[E2 + i];
        int p = atomicAdd(&cur2[d], 1);
        csr2[p] = ei2[i];
      }
    }
    return;
  }

  const int m0 = (blockIdx.x - FB) * 128;
  const int tid = threadIdx.x;
  const int w = tid >> 6, l = tid & 63;
  const int lrow = l >> 3, lslot = l & 7;
  const int wr = w >> 2, wc = w & 3;  // 2x4 wave grid, 64x64 each

  f32x4 acc[4][4] = {};

  for (int k0 = 0; k0 < 256; k0 += 64) {
    const unsigned short* Ap = xb;
    const unsigned short* Bp = gt;
    int ks = k0;

#pragma unroll
    for (int i = 0; i < 2; i++) {
      int row = w * 16 + i * 8 + lrow;
      int gr = m0 + row;
      if (gr >= M) gr = M - 1;
      int g = lslot ^ lrow;
      const unsigned short* src = Ap + (size_t)gr * TD + ks + g * 8;
      unsigned short* dst = sA + (w * 16 + i * 8) * 64;
      __builtin_amdgcn_global_load_lds(
          (const __attribute__((address_space(1))) void*)src,
          (__attribute__((address_space(3))) void*)dst, 16, 0, 0);
    }
#pragma unroll
    for (int i = 0; i < 4; i++) {
      int row = w * 32 + i * 8 + lrow;
      int g = lslot ^ lrow;
      const unsigned short* src = Bp + (size_t)row * TD + ks + g * 8;
      unsigned short* dst = sB + (w * 32 + i * 8) * 64;
      __builtin_amdgcn_global_load_lds(
          (const __attribute__((address_space(1))) void*)src,
          (__attribute__((address_space(3))) void*)dst, 16, 0, 0);
    }
    __syncthreads();

#pragma unroll
    for (int kk = 0; kk < 2; kk++) {
      short8 a[4], b[4];
#pragma unroll
      for (int m = 0; m < 4; m++) {
        int row = wr * 64 + m * 16 + (l & 15);
        int slot = (kk * 4 + (l >> 4)) ^ (row & 7);
        a[m] = *reinterpret_cast<const short8*>(&sA[row * 64 + slot * 8]);
      }
#pragma unroll
      for (int n = 0; n < 4; n++) {
        int row = wc * 64 + n * 16 + (l & 15);
        int slot = (kk * 4 + (l >> 4)) ^ (row & 7);
        b[n] = *reinterpret_cast<const short8*>(&sB[row * 64 + slot * 8]);
      }
#pragma unroll
      for (int m = 0; m < 4; m++)
#pragma unroll
        for (int n = 0; n < 4; n++)
          acc[m][n] =
              __builtin_amdgcn_mfma_f32_16x16x32_bf16(a[m], b[n], acc[m][n], 0, 0, 0);
    }
    __syncthreads();
  }

#pragma unroll
  for (int m = 0; m < 4; m++)
#pragma unroll
    for (int n = 0; n < 4; n++)
#pragma unroll
      for (int j = 0; j < 4; j++) {
        int r = m0 + wr * 64 + m * 16 + (l >> 4) * 4 + j;
        if (r < M)
          qb[(size_t)r * TD + wc * 64 + n * 16 + (l & 15)] = f2bf(acc[m][n][j]);
      }
}

// ===========================================================================
// Fused gather: one wave per node; TWO edges processed concurrently by the
// two 32-lane halves (eh = lane>>5).  Each lane holds 8 dims (ushort8, 16B).
// Score reduce = 5 shfl_xor steps within a half (serves 2 edges at once).
// 2-wide batch -> 4 edges in flight.  Final 8-shfl half-combine per node.
//   aggb[n] = sum_{csr1(n)} x[s]
//   tb[n]   = -sum_{csr2(n)} (q'[n].x[s]) x[s]
// ===========================================================================
__global__ __launch_bounds__(256) void gather_fused_kernel(
    const unsigned short* __restrict__ xb, const unsigned short* __restrict__ qb,
    const int* __restrict__ off1, const int* __restrict__ csr1,
    const int* __restrict__ off2, const int* __restrict__ csr2,
    int N, unsigned short* __restrict__ aggb, unsigned short* __restrict__ tb) {
  int wid = blockIdx.x * 4 + (threadIdx.x >> 6);
  if (wid >= N) return;
  const int lane = threadIdx.x & 63;
  const int eh = lane >> 5;   // edge half 0/1
  const int sl = lane & 31;   // sub-lane: dims [sl*8, sl*8+8)

  // --- graph 1: agg ---
  {
    int beg = off1[wid], end = off1[wid + 1];
    float acc[8] = {};
    for (int j = beg; j < end; j += 4) {
      int e1 = end - 1;
      int j0 = j + eh, j1 = j + 2 + eh;
      int s0 = csr1[j0 < end ? j0 : e1];
      int s1 = csr1[j1 < end ? j1 : e1];
      float k0 = (j0 < end) ? 1.f : 0.f;
      float k1 = (j1 < end) ? 1.f : 0.f;
      ushort8 r0 = *reinterpret_cast<const ushort8*>(xb + (size_t)s0 * TD + sl * 8);
      ushort8 r1 = *reinterpret_cast<const ushort8*>(xb + (size_t)s1 * TD + sl * 8);
#pragma unroll
      for (int i = 0; i < 8; i++)
        acc[i] += k0 * bf2f(r0[i]) + k1 * bf2f(r1[i]);
    }
#pragma unroll
    for (int i = 0; i < 8; i++) acc[i] += __shfl_xor(acc[i], 32, 64);
    if (eh == 0) {
      ushort8 o;
#pragma unroll
      for (int i = 0; i < 8; i++) o[i] = f2bf(acc[i]);
      *reinterpret_cast<ushort8*>(aggb + (size_t)wid * TD + sl * 8) = o;
    }
  }

  // --- graph 2: t = -sum (q'.x[s]) x[s] ---
  {
    ushort8 qv = *reinterpret_cast<const ushort8*>(qb + (size_t)wid * TD + sl * 8);
    float q[8];
#pragma unroll
    for (int i = 0; i < 8; i++) q[i] = bf2f(qv[i]);
    int beg = off2[wid], end = off2[wid + 1];
    float t[8] = {};
    for (int j = beg; j < end; j += 4) {
      int e1 = end - 1;
      int j0 = j + eh, j1 = j + 2 + eh;
      int s0 = csr2[j0 < end ? j0 : e1];
      int s1 = csr2[j1 < end ? j1 : e1];
      float k0 = (j0 < end) ? 1.f : 0.f;
      float k1 = (j1 < end) ? 1.f : 0.f;
      ushort8 r0 = *reinterpret_cast<const ushort8*>(xb + (size_t)s0 * TD + sl * 8);
      ushort8 r1 = *reinterpret_cast<const ushort8*>(xb + (size_t)s1 * TD + sl * 8);
      float x0[8], x1[8];
      float p0 = 0.f, p1 = 0.f;
#pragma unroll
      for (int i = 0; i < 8; i++) {
        x0[i] = bf2f(r0[i]); x1[i] = bf2f(r1[i]);
        p0 += q[i] * x0[i];  p1 += q[i] * x1[i];
      }
#pragma unroll
      for (int m = 1; m < 32; m <<= 1) {
        p0 += __shfl_xor(p0, m, 64);
        p1 += __shfl_xor(p1, m, 64);
      }
      p0 *= k0; p1 *= k1;
#pragma unroll
      for (int i = 0; i < 8; i++) t[i] -= p0 * x0[i] + p1 * x1[i];
    }
#pragma unroll
    for (int i = 0; i < 8; i++) t[i] += __shfl_xor(t[i], 32, 64);
    if (eh == 0) {
      ushort8 o;
#pragma unroll
      for (int i = 0; i < 8; i++) o[i] = f2bf(t[i]);
      *reinterpret_cast<ushort8*>(tb + (size_t)wid * TD + sl * 8) = o;
    }
  }
}

// ===========================================================================
// LDS-staged MFMA GEMM, tile 128x256, 512 thr = 8 waves (2x4 of 64x64).
//   out = xb@W0 + aggb@W1 + tb@Wv   (K=768 segmented, fp32 out, single write)
// KSTEP=64, 16x16x32 bf16 MFMA, global_load_lds(16B) + XOR-(row&7) swizzle.
// (round-5-proven structure; traffic-optimal epilogue — do not split)
// ===========================================================================
__global__ __launch_bounds__(512) void gemm1_kernel(
    const unsigned short* __restrict__ xb, const unsigned short* __restrict__ aggb,
    const unsigned short* __restrict__ tb, const unsigned short* __restrict__ wt,
    float* __restrict__ out, int M) {
  __shared__ __align__(16) unsigned short sA[128 * 64];
  __shared__ __align__(16) unsigned short sB[256 * 64];

  const int m0 = blockIdx.x * 128;
  const int tid = threadIdx.x;
  const int w = tid >> 6, l = tid & 63;
  const int lrow = l >> 3, lslot = l & 7;
  const int wr = w >> 2, wc = w & 3;

  f32x4 acc[4][4] = {};

  for (int k0 = 0; k0 < 768; k0 += 64) {
    int seg = k0 >> 8;  // 0: x@W0, 1: agg@W1, 2: t@Wv
    const unsigned short* Ap = seg == 0 ? xb : seg == 1 ? aggb : tb;
    const unsigned short* Bp = wt + seg * 65536;
    int ks = k0 & 255;

#pragma unroll
    for (int i = 0; i < 2; i++) {
      int row = w * 16 + i * 8 + lrow;
      int gr = m0 + row;
      if (gr >= M) gr = M - 1;
      int g = lslot ^ lrow;
      const unsigned short* src = Ap + (size_t)gr * TD + ks + g * 8;
      unsigned short* dst = sA + (w * 16 + i * 8) * 64;
      __builtin_amdgcn_global_load_lds(
          (const __attribute__((address_space(1))) void*)src,
          (__attribute__((address_space(3))) void*)dst, 16, 0, 0);
    }
#pragma unroll
    for (int i = 0; i < 4; i++) {
      int row = w * 32 + i * 8 + lrow;
      int g = lslot ^ lrow;
      const unsigned short* src = Bp + (size_t)row * TD + ks + g * 8;
      unsigned short* dst = sB + (w * 32 + i * 8) * 64;
      __builtin_amdgcn_global_load_lds(
          (const __attribute__((address_space(1))) void*)src,
          (__attribute__((address_space(3))) void*)dst, 16, 0, 0);
    }
    __syncthreads();

#pragma unroll
    for (int kk = 0; kk < 2; kk++) {
      short8 a[4], b[4];
#pragma unroll
      for (int m = 0; m < 4; m++) {
        int row = wr * 64 + m * 16 + (l & 15);
        int slot = (kk * 4 + (l >> 4)) ^ (row & 7);
        a[m] = *reinterpret_cast<const short8*>(&sA[row * 64 + slot * 8]);
      }
#pragma unroll
      for (int n = 0; n < 4; n++) {
        int row = wc * 64 + n * 16 + (l & 15);
        int slot = (kk * 4 + (l >> 4)) ^ (row & 7);
        b[n] = *reinterpret_cast<const short8*>(&sB[row * 64 + slot * 8]);
      }
#pragma unroll
      for (int m = 0; m < 4; m++)
#pragma unroll
        for (int n = 0; n < 4; n++)
          acc[m][n] =
              __builtin_amdgcn_mfma_f32_16x16x32_bf16(a[m], b[n], acc[m][n], 0, 0, 0);
    }
    __syncthreads();
  }

#pragma unroll
  for (int m = 0; m < 4; m++)
#pragma unroll
    for (int n = 0; n < 4; n++)
#pragma unroll
      for (int j = 0; j < 4; j++) {
        int r = m0 + wr * 64 + m * 16 + (l >> 4) * 4 + j;
        if (r < M)
          out[(size_t)r * TD + wc * 64 + n * 16 + (l & 15)] = acc[m][n][j];
      }
}

// ===========================================================================
extern "C" void kernel_launch(void* const* d_in, const int* in_sizes, int n_in,
                              void* d_out, int out_size, void* d_ws,
                              size_t ws_size, hipStream_t stream) {
  const float* x  = (const float*)d_in[0];
  const int*   ei  = (const int*)d_in[1];
  const int*   ei2 = (const int*)d_in[2];
  const float* W0 = (const float*)d_in[3];
  const float* W1 = (const float*)d_in[4];
  const float* Wq = (const float*)d_in[5];
  const float* Wk = (const float*)d_in[6];
  const float* Wv = (const float*)d_in[7];

  const int N  = in_sizes[0] / TD;
  const int E1 = in_sizes[1] / 2;
  const int E2 = in_sizes[2] / 2;

  float* out = (float*)d_out;
  const size_t rowN = (size_t)N * TD;

  // ---- workspace layout ----
  char* p = (char*)d_ws;
  unsigned short* xb   = (unsigned short*)p; p += rowN * 2;
  unsigned short* aggb = (unsigned short*)p; p += rowN * 2;
  unsigned short* qb   = (unsigned short*)p; p += rowN * 2;
  unsigned short* tb   = (unsigned short*)p; p += rowN * 2;
  unsigned short* wt   = (unsigned short*)p; p += 3 * 65536 * 2;  // W0t,W1t,Wvt
  unsigned short* gt   = (unsigned short*)p; p += 65536 * 2;
  unsigned short* wqb  = (unsigned short*)p; p += 65536 * 2;
  unsigned short* wkb  = (unsigned short*)p; p += 65536 * 2;
  int* off1 = (int*)p; p += (N + 1) * 4;
  int* cur1 = (int*)p; p += N * 4;
  int* off2 = (int*)p; p += (N + 1) * 4;
  int* cur2 = (int*)p; p += N * 4;
  int* csr1 = (int*)p; p += (size_t)E1 * 4;
  int* csr2 = (int*)p; p += (size_t)E2 * 4;
  int* deg1 = (int*)p; p += N * 4;
  int* deg2 = (int*)p; p += N * 4;
  int* bsum = (int*)p; p += 512 * 4;

  // 1. zero degree arrays
  hipMemsetAsync(deg1, 0, (size_t)2 * N * sizeof(int), stream);

  // 2. prologue: hist + all dtype conversions in one dispatch
  long total8 = rowN / 8;
  int nbH = 512;
  int nbX = (int)((total8 + 255) / 256);
  prologue_kernel<<<nbH + nbX + 64 + 768, 256, 0, stream>>>(
      ei, E1, ei2, E2, deg1, deg2, x, xb, total8, Wq, Wk, wqb, wkb, W0, W1, Wv,
      wt, nbH, nbX);

  // 3. scan phase A + G = Wq@Wk^T, then fused prefix+fill of off/cur
  scanA_gemmG_kernel<<<516, 256, 0, stream>>>(deg1, deg2, N, bsum, wqb, wkb, gt);
  scan_fill_kernel<<<512, 256, 0, stream>>>(deg1, deg2, bsum, N, off1, cur1,
                                            off2, cur2);

  // 4. CSR fill  ||  q' = x @ G  (proven GEMM body, merged dispatch)
  int gblk = (N + 127) / 128;
  int FB = 384;
  fill_gemm0_kernel<<<FB + gblk, 512, 0, stream>>>(
      ei, E1, ei2, E2, cur1, cur2, csr1, csr2, xb, gt, qb, N, FB);

  // 5. fused gather: 2 edges per wave via 32-lane halves, 16B/lane
  gather_fused_kernel<<<(N + 3) / 4, 256, 0, stream>>>(xb, qb, off1, csr1,
                                                       off2, csr2, N, aggb, tb);

  // 6. out = x@W0 + agg@W1 + t@Wv   (t already negated; single fp32 write)
  gemm1_kernel<<<gblk, 512, 0, stream>>>(xb, aggb, tb, wt, out, N);
}